// Round 12
// baseline (944.187 us; speedup 1.0000x reference)
//
#include <hip/hip_runtime.h>

// RGCN block-diagonal layer, f32.
// out = relu( (scatter_sum(msg) * norm) + bias + h @ loop_weight )
// msg[e, b*16+o] = sum_i h[src[e], b*16+i] * W[type[e], b*256 + i*16 + o]
//
// v12 = v11 with the precompute M-store widened to float4.
// Evidence: every dword-store stream in this session caps at ~930 GB/s
// (v8 922, v11 931, round-2 atomics 930) while float4 copy hits 6.3 TB/s.
// The block's 16 waves produce node n's 4KB M-block contiguously, so LDS
// st[j*1024 + t*64 + lane] IS M's linear layout: stage 4 nodes (16 KB),
// barrier, stream out as 1 float4/thread.
// Pipeline:
//   A: init kernel   : out = bias + h @ loop_weight        (LDS-staged LW)
//   Z/H: zero + histogram over key = (src/S)*N + dst       (C*N bins)
//   S1/S2/S3: parallel exclusive scan -> row_ptr CSR, cursor
//   C: scatter srec[p] = (src_local<<4)|type  (== M row id)
//   per chunk c: P_c dense precompute M (bf16-packed, wave=type, W in VGPRs)
//                G_c wave-per-dst gather: acc += unpack(M[srec[e]]);
//                    out[d] += acc*norm[d] (non-atomic; ReLU on final pass)

__device__ __forceinline__ unsigned int f2bf(float f) {
  const unsigned int u = __float_as_uint(f);
  return (u + 0x7FFFu + ((u >> 16) & 1u)) >> 16;  // round-nearest-even
}

__global__ __launch_bounds__(256) void rgcn_init_kernel(
    const float* __restrict__ h, const float* __restrict__ loop_w,
    const float* __restrict__ bias, float* __restrict__ out, int N) {
  __shared__ float lw[128 * 128];  // 64 KB
  for (int idx = threadIdx.x; idx < 128 * 128 / 4; idx += 256) {
    ((float4*)lw)[idx] = ((const float4*)loop_w)[idx];
  }
  __syncthreads();

  const int lane = threadIdx.x & 63;
  const int wid = threadIdx.x >> 6;
  const int group0 = blockIdx.x * 4 + wid;
  const int ngroups = gridDim.x * 4;
  const int totgroups = (N + 3) >> 2;
  const float b0 = bias[lane];
  const float b1 = bias[64 + lane];

  for (int g = group0; g < totgroups; g += ngroups) {
    const int n0 = g * 4;
    const int nn = (N - n0 < 4) ? (N - n0) : 4;
    if (nn == 4) {
      const float* __restrict__ r0 = h + (size_t)n0 * 128;
      const float* __restrict__ r1 = r0 + 128;
      const float* __restrict__ r2 = r1 + 128;
      const float* __restrict__ r3 = r2 + 128;
      float a00 = b0, a01 = b1, a10 = b0, a11 = b1;
      float a20 = b0, a21 = b1, a30 = b0, a31 = b1;
#pragma unroll 4
      for (int k = 0; k < 128; ++k) {
        const float w0 = lw[k * 128 + lane];
        const float w1 = lw[k * 128 + 64 + lane];
        a00 = fmaf(r0[k], w0, a00); a01 = fmaf(r0[k], w1, a01);
        a10 = fmaf(r1[k], w0, a10); a11 = fmaf(r1[k], w1, a11);
        a20 = fmaf(r2[k], w0, a20); a21 = fmaf(r2[k], w1, a21);
        a30 = fmaf(r3[k], w0, a30); a31 = fmaf(r3[k], w1, a31);
      }
      float* __restrict__ o0 = out + (size_t)n0 * 128;
      o0[lane] = a00;        o0[64 + lane] = a01;
      o0[128 + lane] = a10;  o0[192 + lane] = a11;
      o0[256 + lane] = a20;  o0[320 + lane] = a21;
      o0[384 + lane] = a30;  o0[448 + lane] = a31;
    } else {
      for (int r = 0; r < nn; ++r) {
        const int n = n0 + r;
        const float* __restrict__ hr = h + (size_t)n * 128;
        float a0 = b0, a1 = b1;
#pragma unroll 4
        for (int k = 0; k < 128; ++k) {
          const float a = hr[k];
          a0 = fmaf(a, lw[k * 128 + lane], a0);
          a1 = fmaf(a, lw[k * 128 + 64 + lane], a1);
        }
        out[(size_t)n * 128 + lane] = a0;
        out[(size_t)n * 128 + 64 + lane] = a1;
      }
    }
  }
}

// Phase P_c: wave = one relation type (weights in 32 VGPRs). Groups of 4
// nodes: compute (4 independent chains), stage packed dwords in LDS (LDS
// layout == M linear layout), then stream 16 KB out as float4/thread.
__global__ __launch_bounds__(1024) void rgcn_precompute_kernel(
    const float* __restrict__ h, const float* __restrict__ weight,
    unsigned int* __restrict__ M, int base, int cend) {
  __shared__ unsigned int st[4 * 1024];  // 16 KB = 4 nodes x 16 types x 256 B
  const int tid = threadIdx.x;
  const int lane = tid & 63;
  const int t = tid >> 6;  // wave index = type 0..15
  const int b = lane >> 4;
  const int o = lane & 15;

  const float* __restrict__ wb = weight + t * 2048 + b * 256 + o;
  float wlo[16], whi[16];
#pragma unroll
  for (int i = 0; i < 16; ++i) {
    wlo[i] = wb[i * 16];
    whi[i] = wb[1024 + i * 16];
  }

  const int span = cend - base;
  const int ngroups = (span + 3) >> 2;

  for (int g = blockIdx.x; g < ngroups; g += gridDim.x) {
    const int n0 = base + g * 4;
#pragma unroll
    for (int j = 0; j < 4; ++j) {
      const int n = n0 + j;
      unsigned int pk = 0;
      if (n < cend) {
        const float4* __restrict__ hp =
            (const float4*)(h + (size_t)n * 128) + (b << 2);
        const float4 x0 = hp[0], x1 = hp[1], x2 = hp[2], x3 = hp[3];
        const float4 y0 = hp[16], y1 = hp[17], y2 = hp[18], y3 = hp[19];

        float a0 = x0.x * wlo[0], a1 = x0.y * wlo[1];
        a0 = fmaf(x0.z, wlo[2], a0);  a1 = fmaf(x0.w, wlo[3], a1);
        a0 = fmaf(x1.x, wlo[4], a0);  a1 = fmaf(x1.y, wlo[5], a1);
        a0 = fmaf(x1.z, wlo[6], a0);  a1 = fmaf(x1.w, wlo[7], a1);
        a0 = fmaf(x2.x, wlo[8], a0);  a1 = fmaf(x2.y, wlo[9], a1);
        a0 = fmaf(x2.z, wlo[10], a0); a1 = fmaf(x2.w, wlo[11], a1);
        a0 = fmaf(x3.x, wlo[12], a0); a1 = fmaf(x3.y, wlo[13], a1);
        a0 = fmaf(x3.z, wlo[14], a0); a1 = fmaf(x3.w, wlo[15], a1);

        float c0 = y0.x * whi[0], c1 = y0.y * whi[1];
        c0 = fmaf(y0.z, whi[2], c0);  c1 = fmaf(y0.w, whi[3], c1);
        c0 = fmaf(y1.x, whi[4], c0);  c1 = fmaf(y1.y, whi[5], c1);
        c0 = fmaf(y1.z, whi[6], c0);  c1 = fmaf(y1.w, whi[7], c1);
        c0 = fmaf(y2.x, whi[8], c0);  c1 = fmaf(y2.y, whi[9], c1);
        c0 = fmaf(y2.z, whi[10], c0); c1 = fmaf(y2.w, whi[11], c1);
        c0 = fmaf(y3.x, whi[12], c0); c1 = fmaf(y3.y, whi[13], c1);
        c0 = fmaf(y3.z, whi[14], c0); c1 = fmaf(y3.w, whi[15], c1);

        pk = f2bf(a0 + a1) | (f2bf(c0 + c1) << 16);
      }
      st[j * 1024 + tid] = pk;
    }
    __syncthreads();

    const size_t dst = ((size_t)(n0 - base)) << 10;  // dword offset
    if (n0 + 4 <= cend) {
      ((float4*)(M + dst))[tid] = ((const float4*)st)[tid];
    } else {
      const int valid = (cend - n0) << 10;  // dwords
      for (int k = tid; k < valid; k += 1024) M[dst + k] = st[k];
    }
    __syncthreads();
  }
}

__global__ __launch_bounds__(256) void rgcn_zero_kernel(int* __restrict__ p,
                                                        int n) {
  for (int i = blockIdx.x * 256 + threadIdx.x; i < n; i += gridDim.x * 256)
    p[i] = 0;
}

__global__ __launch_bounds__(256) void rgcn_hist_kernel(
    const int* __restrict__ esrc, const int* __restrict__ edst,
    int* __restrict__ cnt, int E, int N, unsigned S) {
  for (int e = blockIdx.x * 256 + threadIdx.x; e < E; e += gridDim.x * 256) {
    const unsigned q = (unsigned)esrc[e] / S;
    atomicAdd(&cnt[(int)(q * (unsigned)N) + edst[e]], 1);
  }
}

// ---- parallel exclusive scan over bins (3 kernels) ----
__global__ __launch_bounds__(1024) void rgcn_scan_pass1(
    const int* __restrict__ cnt, int* __restrict__ partial, int bins) {
  __shared__ int sums[1024];
  const int t = threadIdx.x;
  const int base = blockIdx.x * 4096 + t * 4;
  int s = 0;
  if (base + 3 < bins) {
    const int4 v = *(const int4*)(cnt + base);
    s = v.x + v.y + v.z + v.w;
  } else {
    for (int j = 0; j < 4; ++j)
      if (base + j < bins) s += cnt[base + j];
  }
  sums[t] = s;
  __syncthreads();
  for (int off = 512; off > 0; off >>= 1) {
    if (t < off) sums[t] += sums[t + off];
    __syncthreads();
  }
  if (t == 0) partial[blockIdx.x] = sums[0];
}

__global__ __launch_bounds__(1024) void rgcn_scan_pass2(
    int* __restrict__ partial, int nb) {
  __shared__ int sc[1024];
  const int t = threadIdx.x;
  int v[4];
  int s = 0;
#pragma unroll
  for (int j = 0; j < 4; ++j) {
    const int i = t * 4 + j;
    v[j] = (i < nb) ? partial[i] : 0;
    s += v[j];
  }
  sc[t] = s;
  __syncthreads();
#pragma unroll
  for (int off = 1; off < 1024; off <<= 1) {
    const int add = (t >= off) ? sc[t - off] : 0;
    __syncthreads();
    sc[t] += add;
    __syncthreads();
  }
  int run = (t == 0) ? 0 : sc[t - 1];
#pragma unroll
  for (int j = 0; j < 4; ++j) {
    const int i = t * 4 + j;
    if (i < nb) partial[i] = run;
    run += v[j];
  }
}

__global__ __launch_bounds__(1024) void rgcn_scan_pass3(
    const int* __restrict__ cnt, const int* __restrict__ partial,
    int* __restrict__ row_ptr, int* __restrict__ cursor, int bins) {
  __shared__ int sums[1024];
  const int t = threadIdx.x;
  const int base = blockIdx.x * 4096 + t * 4;
  int v0 = 0, v1 = 0, v2 = 0, v3 = 0;
  if (base + 3 < bins) {
    const int4 v = *(const int4*)(cnt + base);
    v0 = v.x; v1 = v.y; v2 = v.z; v3 = v.w;
  } else {
    if (base < bins) v0 = cnt[base];
    if (base + 1 < bins) v1 = cnt[base + 1];
    if (base + 2 < bins) v2 = cnt[base + 2];
  }
  sums[t] = v0 + v1 + v2 + v3;
  __syncthreads();
#pragma unroll
  for (int off = 1; off < 1024; off <<= 1) {
    const int add = (t >= off) ? sums[t - off] : 0;
    __syncthreads();
    sums[t] += add;
    __syncthreads();
  }
  const int run = partial[blockIdx.x] + ((t == 0) ? 0 : sums[t - 1]);
  const int p0 = run, p1 = p0 + v0, p2 = p1 + v1, p3 = p2 + v2;
  if (base + 3 < bins) {
    *(int4*)(row_ptr + base) = make_int4(p0, p1, p2, p3);
    *(int4*)(cursor + base) = make_int4(p0, p1, p2, p3);
  } else {
    if (base < bins) { row_ptr[base] = p0; cursor[base] = p0; }
    if (base + 1 < bins) { row_ptr[base + 1] = p1; cursor[base + 1] = p1; }
    if (base + 2 < bins) { row_ptr[base + 2] = p2; cursor[base + 2] = p2; }
  }
}

__global__ void rgcn_set_kernel(int* __restrict__ p, int v) {
  if (threadIdx.x == 0) *p = v;
}
// -------------------------------------------------------

__global__ __launch_bounds__(256) void rgcn_scatter_kernel(
    const int* __restrict__ esrc, const int* __restrict__ edst,
    const int* __restrict__ etype, int* __restrict__ cursor,
    int* __restrict__ srec, int E, int N, unsigned S) {
  for (int e = blockIdx.x * 256 + threadIdx.x; e < E; e += gridDim.x * 256) {
    const unsigned s = (unsigned)esrc[e];
    const unsigned q = s / S;
    const int key = (int)(q * (unsigned)N) + edst[e];
    const int p = atomicAdd(&cursor[key], 1);
    srec[p] = (int)((s - q * S) << 4) | etype[e];
  }
}

// Phase G_c: grid-strided, one wave per dst. Per edge: ONE coalesced dword
// load of the bf16-packed message row. 8-wide batches for MLP.
__global__ __launch_bounds__(256) void rgcn_gather3_kernel(
    const float* __restrict__ norm, const int* __restrict__ srec,
    const int* __restrict__ rpc, const unsigned int* __restrict__ M,
    float* __restrict__ out, int N, int final_pass) {
  const int lane = threadIdx.x & 63;
  const int w0 = blockIdx.x * 4 + (threadIdx.x >> 6);
  const int nw = gridDim.x * 4;

  for (int d = w0; d < N; d += nw) {
    const int e0 = rpc[d];
    const int e1 = rpc[d + 1];
    if (!final_pass && e0 == e1) continue;

    float acc0 = 0.f, acc1 = 0.f;
    int e = e0;
    for (; e + 8 <= e1; e += 8) {
      const int r0 = srec[e], r1 = srec[e + 1], r2 = srec[e + 2],
                r3 = srec[e + 3], r4 = srec[e + 4], r5 = srec[e + 5],
                r6 = srec[e + 6], r7 = srec[e + 7];
      const unsigned int v0 = M[(size_t)r0 * 64 + lane];
      const unsigned int v1 = M[(size_t)r1 * 64 + lane];
      const unsigned int v2 = M[(size_t)r2 * 64 + lane];
      const unsigned int v3 = M[(size_t)r3 * 64 + lane];
      const unsigned int v4 = M[(size_t)r4 * 64 + lane];
      const unsigned int v5 = M[(size_t)r5 * 64 + lane];
      const unsigned int v6 = M[(size_t)r6 * 64 + lane];
      const unsigned int v7 = M[(size_t)r7 * 64 + lane];
      acc0 += __uint_as_float(v0 << 16);
      acc1 += __uint_as_float(v0 & 0xFFFF0000u);
      acc0 += __uint_as_float(v1 << 16);
      acc1 += __uint_as_float(v1 & 0xFFFF0000u);
      acc0 += __uint_as_float(v2 << 16);
      acc1 += __uint_as_float(v2 & 0xFFFF0000u);
      acc0 += __uint_as_float(v3 << 16);
      acc1 += __uint_as_float(v3 & 0xFFFF0000u);
      acc0 += __uint_as_float(v4 << 16);
      acc1 += __uint_as_float(v4 & 0xFFFF0000u);
      acc0 += __uint_as_float(v5 << 16);
      acc1 += __uint_as_float(v5 & 0xFFFF0000u);
      acc0 += __uint_as_float(v6 << 16);
      acc1 += __uint_as_float(v6 & 0xFFFF0000u);
      acc0 += __uint_as_float(v7 << 16);
      acc1 += __uint_as_float(v7 & 0xFFFF0000u);
    }
    for (; e + 4 <= e1; e += 4) {
      const int r0 = srec[e], r1 = srec[e + 1], r2 = srec[e + 2],
                r3 = srec[e + 3];
      const unsigned int v0 = M[(size_t)r0 * 64 + lane];
      const unsigned int v1 = M[(size_t)r1 * 64 + lane];
      const unsigned int v2 = M[(size_t)r2 * 64 + lane];
      const unsigned int v3 = M[(size_t)r3 * 64 + lane];
      acc0 += __uint_as_float(v0 << 16);
      acc1 += __uint_as_float(v0 & 0xFFFF0000u);
      acc0 += __uint_as_float(v1 << 16);
      acc1 += __uint_as_float(v1 & 0xFFFF0000u);
      acc0 += __uint_as_float(v2 << 16);
      acc1 += __uint_as_float(v2 & 0xFFFF0000u);
      acc0 += __uint_as_float(v3 << 16);
      acc1 += __uint_as_float(v3 & 0xFFFF0000u);
    }
    for (; e < e1; ++e) {
      const unsigned int v = M[(size_t)srec[e] * 64 + lane];
      acc0 += __uint_as_float(v << 16);
      acc1 += __uint_as_float(v & 0xFFFF0000u);
    }

    const float nm = norm[d];
    float* __restrict__ op = out + ((size_t)d << 7);
    float o0 = fmaf(acc0, nm, op[lane]);
    float o1 = fmaf(acc1, nm, op[64 + lane]);
    if (final_pass) {
      o0 = fmaxf(o0, 0.f);
      o1 = fmaxf(o1, 0.f);
    }
    op[lane] = o0;
    op[64 + lane] = o1;
  }
}

// Fallback (ws too small / unexpected shape): unsorted atomic edge kernel.
__global__ __launch_bounds__(256) void rgcn_edge_kernel(
    const float* __restrict__ h, const float* __restrict__ norm,
    const int* __restrict__ esrc, const int* __restrict__ edst,
    const int* __restrict__ etype, const float* __restrict__ weight,
    float* __restrict__ out, int E) {
  const int lane = threadIdx.x & 63;
  const int wid = threadIdx.x >> 6;
  const int wave0 = blockIdx.x * 4 + wid;
  const int nwaves = gridDim.x * 4;
  const int b = lane >> 4;
  const int o = lane & 15;

  for (int e = wave0; e < E; e += nwaves) {
    const int src = esrc[e];
    const int dst = edst[e];
    const int et = etype[e];
    const float s_lo = h[src * 128 + lane];
    const float s_hi = h[src * 128 + 64 + lane];
    const float nrm = norm[dst];
    const float* __restrict__ Wb = weight + et * 2048 + b * 256 + o;
    float m0 = 0.f, m1 = 0.f;
#pragma unroll
    for (int i = 0; i < 16; ++i) {
      const float a_lo = __shfl(s_lo, (lane & 48) + i, 64);
      const float a_hi = __shfl(s_hi, (lane & 48) + i, 64);
      m0 = fmaf(a_lo, Wb[i * 16], m0);
      m1 = fmaf(a_hi, Wb[1024 + i * 16], m1);
    }
    atomicAdd(&out[dst * 128 + lane], m0 * nrm);
    atomicAdd(&out[dst * 128 + 64 + lane], m1 * nrm);
  }
}

__global__ __launch_bounds__(256) void rgcn_relu_kernel(float* __restrict__ out,
                                                        int total4) {
  int i = blockIdx.x * 256 + threadIdx.x;
  const int stride = gridDim.x * 256;
  for (; i < total4; i += stride) {
    float4 v = ((float4*)out)[i];
    v.x = fmaxf(v.x, 0.f);
    v.y = fmaxf(v.y, 0.f);
    v.z = fmaxf(v.z, 0.f);
    v.w = fmaxf(v.w, 0.f);
    ((float4*)out)[i] = v;
  }
}

extern "C" void kernel_launch(void* const* d_in, const int* in_sizes, int n_in,
                              void* d_out, int out_size, void* d_ws, size_t ws_size,
                              hipStream_t stream) {
  const float* h      = (const float*)d_in[0];
  const float* norm   = (const float*)d_in[1];
  const int*   esrc   = (const int*)d_in[2];
  const int*   edst   = (const int*)d_in[3];
  const int*   etype  = (const int*)d_in[4];
  const float* weight = (const float*)d_in[5];
  const float* bias   = (const float*)d_in[6];
  const float* loop_w = (const float*)d_in[7];
  float* out = (float*)d_out;

  const int N = in_sizes[0] / 128;
  const int E = in_sizes[2];
  const int nrels = in_sizes[5] / 2048;

  rgcn_init_kernel<<<2048, 256, 0, stream>>>(h, loop_w, bias, out, N);

  // Pick the SMALLEST C (fewest passes) with S=ceil(N/C) whose footprint
  // fits ws_size. ws (dwords): cnt[bins] | row_ptr[bins+1] | cursor[bins] |
  // partial[4096] | srec[E] | M[S*16*64]
  int C = -1, S = 0;
  size_t ofs_rp = 0, ofs_cur = 0, ofs_part = 0, ofs_srec = 0, ofs_M = 0;
  if (nrels == 16 && N >= 1 && N < (1 << 26)) {
    for (int cc = 1; cc <= 64; ++cc) {
      const size_t bins = (size_t)cc * (size_t)N;
      if (bins > (size_t)4096 * 4096) break;  // scan capacity
      const int ss = (N + cc - 1) / cc;
      const size_t o_rp = (bins + 3) & ~(size_t)3;
      const size_t o_cur = (o_rp + bins + 1 + 3) & ~(size_t)3;
      const size_t o_part = (o_cur + bins + 3) & ~(size_t)3;
      const size_t o_srec = o_part + 4096;
      const size_t o_M = (o_srec + (size_t)E + 15) & ~(size_t)15;
      const size_t need = (o_M + (size_t)ss * 16 * 64) * 4;
      if (need <= ws_size) {
        C = cc; S = ss;
        ofs_rp = o_rp; ofs_cur = o_cur; ofs_part = o_part;
        ofs_srec = o_srec; ofs_M = o_M;
        break;
      }
    }
  }

  if (C >= 1) {
    const int bins = C * N;
    const int nb = (bins + 4095) / 4096;
    int* base    = (int*)d_ws;
    int* cnt     = base;
    int* row_ptr = base + ofs_rp;
    int* cursor  = base + ofs_cur;
    int* partial = base + ofs_part;
    int* srec    = base + ofs_srec;
    unsigned int* M = (unsigned int*)(base + ofs_M);

    rgcn_zero_kernel<<<1024, 256, 0, stream>>>(cnt, bins);
    rgcn_hist_kernel<<<2048, 256, 0, stream>>>(esrc, edst, cnt, E, N,
                                               (unsigned)S);
    rgcn_scan_pass1<<<nb, 1024, 0, stream>>>(cnt, partial, bins);
    rgcn_scan_pass2<<<1, 1024, 0, stream>>>(partial, nb);
    rgcn_scan_pass3<<<nb, 1024, 0, stream>>>(cnt, partial, row_ptr, cursor,
                                             bins);
    rgcn_set_kernel<<<1, 64, 0, stream>>>(row_ptr + bins, E);
    rgcn_scatter_kernel<<<2048, 256, 0, stream>>>(esrc, edst, etype, cursor,
                                                  srec, E, N, (unsigned)S);
    for (int c = 0; c < C; ++c) {
      const int cbase = c * S;
      const int cend = (cbase + S < N) ? (cbase + S) : N;
      if (cbase >= N) break;
      rgcn_precompute_kernel<<<512, 1024, 0, stream>>>(h, weight, M, cbase,
                                                       cend);
      rgcn_gather3_kernel<<<2048, 256, 0, stream>>>(
          norm, srec, row_ptr + (size_t)c * N, M, out, N,
          (c == C - 1) ? 1 : 0);
    }
  } else {
    rgcn_edge_kernel<<<4096, 256, 0, stream>>>(h, norm, esrc, edst, etype,
                                               weight, out, E);
    rgcn_relu_kernel<<<2048, 256, 0, stream>>>(out, (N * 128) / 4);
  }
}

// Round 14
// 887.085 us; speedup vs baseline: 1.0644x; 1.0644x over previous
//
#include <hip/hip_runtime.h>

// RGCN block-diagonal layer, f32.
// out = relu( (scatter_sum(msg) * norm) + bias + h @ loop_weight )
// msg[e, b*16+o] = sum_i h[src[e], b*16+i] * W[type[e], b*256 + i*16 + o]
//
// v14 = v13 with the NT-store compile fix: __builtin_nontemporal_store
// requires a NATIVE vector type (ext_vector_type), not HIP's float4 class.
// Theory under test (from r11/r12 evidence): M write rate pinned ~900 GB/s
// across occupancy 42-80%, dword vs float4, LDS-staged or not -> saturated
// L2 dirty-eviction path. M is written once, read once: NT store + NT load.
// Pipeline:
//   A: init kernel   : out = bias + h @ loop_weight        (LDS-staged LW)
//   Z/H: zero + histogram over key = (src/S)*N + dst       (C*N bins)
//   S1/S2/S3: parallel exclusive scan -> row_ptr CSR, cursor
//   C: scatter srec[p] = (src_local<<4)|type  (== M row id)
//   per chunk c: P_c dense precompute M (bf16-packed, wave=type, W in VGPRs)
//                G_c wave-per-dst gather: acc += unpack(M[srec[e]]);
//                    out[d] += acc*norm[d] (non-atomic; ReLU on final pass)

typedef float nfloat4 __attribute__((ext_vector_type(4)));

__device__ __forceinline__ unsigned int f2bf(float f) {
  const unsigned int u = __float_as_uint(f);
  return (u + 0x7FFFu + ((u >> 16) & 1u)) >> 16;  // round-nearest-even
}

__global__ __launch_bounds__(256) void rgcn_init_kernel(
    const float* __restrict__ h, const float* __restrict__ loop_w,
    const float* __restrict__ bias, float* __restrict__ out, int N) {
  __shared__ float lw[128 * 128];  // 64 KB
  for (int idx = threadIdx.x; idx < 128 * 128 / 4; idx += 256) {
    ((float4*)lw)[idx] = ((const float4*)loop_w)[idx];
  }
  __syncthreads();

  const int lane = threadIdx.x & 63;
  const int wid = threadIdx.x >> 6;
  const int group0 = blockIdx.x * 4 + wid;
  const int ngroups = gridDim.x * 4;
  const int totgroups = (N + 3) >> 2;
  const float b0 = bias[lane];
  const float b1 = bias[64 + lane];

  for (int g = group0; g < totgroups; g += ngroups) {
    const int n0 = g * 4;
    const int nn = (N - n0 < 4) ? (N - n0) : 4;
    if (nn == 4) {
      const float* __restrict__ r0 = h + (size_t)n0 * 128;
      const float* __restrict__ r1 = r0 + 128;
      const float* __restrict__ r2 = r1 + 128;
      const float* __restrict__ r3 = r2 + 128;
      float a00 = b0, a01 = b1, a10 = b0, a11 = b1;
      float a20 = b0, a21 = b1, a30 = b0, a31 = b1;
#pragma unroll 4
      for (int k = 0; k < 128; ++k) {
        const float w0 = lw[k * 128 + lane];
        const float w1 = lw[k * 128 + 64 + lane];
        a00 = fmaf(r0[k], w0, a00); a01 = fmaf(r0[k], w1, a01);
        a10 = fmaf(r1[k], w0, a10); a11 = fmaf(r1[k], w1, a11);
        a20 = fmaf(r2[k], w0, a20); a21 = fmaf(r2[k], w1, a21);
        a30 = fmaf(r3[k], w0, a30); a31 = fmaf(r3[k], w1, a31);
      }
      float* __restrict__ o0 = out + (size_t)n0 * 128;
      o0[lane] = a00;        o0[64 + lane] = a01;
      o0[128 + lane] = a10;  o0[192 + lane] = a11;
      o0[256 + lane] = a20;  o0[320 + lane] = a21;
      o0[384 + lane] = a30;  o0[448 + lane] = a31;
    } else {
      for (int r = 0; r < nn; ++r) {
        const int n = n0 + r;
        const float* __restrict__ hr = h + (size_t)n * 128;
        float a0 = b0, a1 = b1;
#pragma unroll 4
        for (int k = 0; k < 128; ++k) {
          const float a = hr[k];
          a0 = fmaf(a, lw[k * 128 + lane], a0);
          a1 = fmaf(a, lw[k * 128 + 64 + lane], a1);
        }
        out[(size_t)n * 128 + lane] = a0;
        out[(size_t)n * 128 + 64 + lane] = a1;
      }
    }
  }
}

// Phase P_c: wave = one relation type (weights in 32 VGPRs). Groups of 4
// nodes: compute (4 independent chains), stage packed dwords in LDS (LDS
// layout == M linear layout), then stream 16 KB out with NON-TEMPORAL
// native-vec4 stores (bypass L2 -- M is written once, read once).
__global__ __launch_bounds__(1024) void rgcn_precompute_kernel(
    const float* __restrict__ h, const float* __restrict__ weight,
    unsigned int* __restrict__ M, int base, int cend) {
  __shared__ unsigned int st[4 * 1024];  // 16 KB = 4 nodes x 16 types x 256 B
  const int tid = threadIdx.x;
  const int lane = tid & 63;
  const int t = tid >> 6;  // wave index = type 0..15
  const int b = lane >> 4;
  const int o = lane & 15;

  const float* __restrict__ wb = weight + t * 2048 + b * 256 + o;
  float wlo[16], whi[16];
#pragma unroll
  for (int i = 0; i < 16; ++i) {
    wlo[i] = wb[i * 16];
    whi[i] = wb[1024 + i * 16];
  }

  const int span = cend - base;
  const int ngroups = (span + 3) >> 2;

  for (int g = blockIdx.x; g < ngroups; g += gridDim.x) {
    const int n0 = base + g * 4;
#pragma unroll
    for (int j = 0; j < 4; ++j) {
      const int n = n0 + j;
      unsigned int pk = 0;
      if (n < cend) {
        const float4* __restrict__ hp =
            (const float4*)(h + (size_t)n * 128) + (b << 2);
        const float4 x0 = hp[0], x1 = hp[1], x2 = hp[2], x3 = hp[3];
        const float4 y0 = hp[16], y1 = hp[17], y2 = hp[18], y3 = hp[19];

        float a0 = x0.x * wlo[0], a1 = x0.y * wlo[1];
        a0 = fmaf(x0.z, wlo[2], a0);  a1 = fmaf(x0.w, wlo[3], a1);
        a0 = fmaf(x1.x, wlo[4], a0);  a1 = fmaf(x1.y, wlo[5], a1);
        a0 = fmaf(x1.z, wlo[6], a0);  a1 = fmaf(x1.w, wlo[7], a1);
        a0 = fmaf(x2.x, wlo[8], a0);  a1 = fmaf(x2.y, wlo[9], a1);
        a0 = fmaf(x2.z, wlo[10], a0); a1 = fmaf(x2.w, wlo[11], a1);
        a0 = fmaf(x3.x, wlo[12], a0); a1 = fmaf(x3.y, wlo[13], a1);
        a0 = fmaf(x3.z, wlo[14], a0); a1 = fmaf(x3.w, wlo[15], a1);

        float c0 = y0.x * whi[0], c1 = y0.y * whi[1];
        c0 = fmaf(y0.z, whi[2], c0);  c1 = fmaf(y0.w, whi[3], c1);
        c0 = fmaf(y1.x, whi[4], c0);  c1 = fmaf(y1.y, whi[5], c1);
        c0 = fmaf(y1.z, whi[6], c0);  c1 = fmaf(y1.w, whi[7], c1);
        c0 = fmaf(y2.x, whi[8], c0);  c1 = fmaf(y2.y, whi[9], c1);
        c0 = fmaf(y2.z, whi[10], c0); c1 = fmaf(y2.w, whi[11], c1);
        c0 = fmaf(y3.x, whi[12], c0); c1 = fmaf(y3.y, whi[13], c1);
        c0 = fmaf(y3.z, whi[14], c0); c1 = fmaf(y3.w, whi[15], c1);

        pk = f2bf(a0 + a1) | (f2bf(c0 + c1) << 16);
      }
      st[j * 1024 + tid] = pk;
    }
    __syncthreads();

    const size_t dst = ((size_t)(n0 - base)) << 10;  // dword offset
    if (n0 + 4 <= cend) {
      const nfloat4 v = ((const nfloat4*)st)[tid];
      __builtin_nontemporal_store(v, ((nfloat4*)(M + dst)) + tid);
    } else {
      const int valid = (cend - n0) << 10;  // dwords
      for (int k = tid; k < valid; k += 1024) M[dst + k] = st[k];
    }
    __syncthreads();
  }
}

__global__ __launch_bounds__(256) void rgcn_zero_kernel(int* __restrict__ p,
                                                        int n) {
  for (int i = blockIdx.x * 256 + threadIdx.x; i < n; i += gridDim.x * 256)
    p[i] = 0;
}

__global__ __launch_bounds__(256) void rgcn_hist_kernel(
    const int* __restrict__ esrc, const int* __restrict__ edst,
    int* __restrict__ cnt, int E, int N, unsigned S) {
  for (int e = blockIdx.x * 256 + threadIdx.x; e < E; e += gridDim.x * 256) {
    const unsigned q = (unsigned)esrc[e] / S;
    atomicAdd(&cnt[(int)(q * (unsigned)N) + edst[e]], 1);
  }
}

// ---- parallel exclusive scan over bins (3 kernels) ----
__global__ __launch_bounds__(1024) void rgcn_scan_pass1(
    const int* __restrict__ cnt, int* __restrict__ partial, int bins) {
  __shared__ int sums[1024];
  const int t = threadIdx.x;
  const int base = blockIdx.x * 4096 + t * 4;
  int s = 0;
  if (base + 3 < bins) {
    const int4 v = *(const int4*)(cnt + base);
    s = v.x + v.y + v.z + v.w;
  } else {
    for (int j = 0; j < 4; ++j)
      if (base + j < bins) s += cnt[base + j];
  }
  sums[t] = s;
  __syncthreads();
  for (int off = 512; off > 0; off >>= 1) {
    if (t < off) sums[t] += sums[t + off];
    __syncthreads();
  }
  if (t == 0) partial[blockIdx.x] = sums[0];
}

__global__ __launch_bounds__(1024) void rgcn_scan_pass2(
    int* __restrict__ partial, int nb) {
  __shared__ int sc[1024];
  const int t = threadIdx.x;
  int v[4];
  int s = 0;
#pragma unroll
  for (int j = 0; j < 4; ++j) {
    const int i = t * 4 + j;
    v[j] = (i < nb) ? partial[i] : 0;
    s += v[j];
  }
  sc[t] = s;
  __syncthreads();
#pragma unroll
  for (int off = 1; off < 1024; off <<= 1) {
    const int add = (t >= off) ? sc[t - off] : 0;
    __syncthreads();
    sc[t] += add;
    __syncthreads();
  }
  int run = (t == 0) ? 0 : sc[t - 1];
#pragma unroll
  for (int j = 0; j < 4; ++j) {
    const int i = t * 4 + j;
    if (i < nb) partial[i] = run;
    run += v[j];
  }
}

__global__ __launch_bounds__(1024) void rgcn_scan_pass3(
    const int* __restrict__ cnt, const int* __restrict__ partial,
    int* __restrict__ row_ptr, int* __restrict__ cursor, int bins) {
  __shared__ int sums[1024];
  const int t = threadIdx.x;
  const int base = blockIdx.x * 4096 + t * 4;
  int v0 = 0, v1 = 0, v2 = 0, v3 = 0;
  if (base + 3 < bins) {
    const int4 v = *(const int4*)(cnt + base);
    v0 = v.x; v1 = v.y; v2 = v.z; v3 = v.w;
  } else {
    if (base < bins) v0 = cnt[base];
    if (base + 1 < bins) v1 = cnt[base + 1];
    if (base + 2 < bins) v2 = cnt[base + 2];
  }
  sums[t] = v0 + v1 + v2 + v3;
  __syncthreads();
#pragma unroll
  for (int off = 1; off < 1024; off <<= 1) {
    const int add = (t >= off) ? sums[t - off] : 0;
    __syncthreads();
    sums[t] += add;
    __syncthreads();
  }
  const int run = partial[blockIdx.x] + ((t == 0) ? 0 : sums[t - 1]);
  const int p0 = run, p1 = p0 + v0, p2 = p1 + v1, p3 = p2 + v2;
  if (base + 3 < bins) {
    *(int4*)(row_ptr + base) = make_int4(p0, p1, p2, p3);
    *(int4*)(cursor + base) = make_int4(p0, p1, p2, p3);
  } else {
    if (base < bins) { row_ptr[base] = p0; cursor[base] = p0; }
    if (base + 1 < bins) { row_ptr[base + 1] = p1; cursor[base + 1] = p1; }
    if (base + 2 < bins) { row_ptr[base + 2] = p2; cursor[base + 2] = p2; }
  }
}

__global__ void rgcn_set_kernel(int* __restrict__ p, int v) {
  if (threadIdx.x == 0) *p = v;
}
// -------------------------------------------------------

__global__ __launch_bounds__(256) void rgcn_scatter_kernel(
    const int* __restrict__ esrc, const int* __restrict__ edst,
    const int* __restrict__ etype, int* __restrict__ cursor,
    int* __restrict__ srec, int E, int N, unsigned S) {
  for (int e = blockIdx.x * 256 + threadIdx.x; e < E; e += gridDim.x * 256) {
    const unsigned s = (unsigned)esrc[e];
    const unsigned q = s / S;
    const int key = (int)(q * (unsigned)N) + edst[e];
    const int p = atomicAdd(&cursor[key], 1);
    srec[p] = (int)((s - q * S) << 4) | etype[e];
  }
}

// Phase G_c: grid-strided, one wave per dst. Per edge: ONE coalesced
// NON-TEMPORAL dword load of the bf16-packed message row (each M row is
// read ~once; caching it only pollutes L2). 8-wide batches for MLP.
__global__ __launch_bounds__(256) void rgcn_gather3_kernel(
    const float* __restrict__ norm, const int* __restrict__ srec,
    const int* __restrict__ rpc, const unsigned int* __restrict__ M,
    float* __restrict__ out, int N, int final_pass) {
  const int lane = threadIdx.x & 63;
  const int w0 = blockIdx.x * 4 + (threadIdx.x >> 6);
  const int nw = gridDim.x * 4;

  for (int d = w0; d < N; d += nw) {
    const int e0 = rpc[d];
    const int e1 = rpc[d + 1];
    if (!final_pass && e0 == e1) continue;

    float acc0 = 0.f, acc1 = 0.f;
    int e = e0;
    for (; e + 8 <= e1; e += 8) {
      const int r0 = srec[e], r1 = srec[e + 1], r2 = srec[e + 2],
                r3 = srec[e + 3], r4 = srec[e + 4], r5 = srec[e + 5],
                r6 = srec[e + 6], r7 = srec[e + 7];
      const unsigned int v0 = __builtin_nontemporal_load(&M[(size_t)r0 * 64 + lane]);
      const unsigned int v1 = __builtin_nontemporal_load(&M[(size_t)r1 * 64 + lane]);
      const unsigned int v2 = __builtin_nontemporal_load(&M[(size_t)r2 * 64 + lane]);
      const unsigned int v3 = __builtin_nontemporal_load(&M[(size_t)r3 * 64 + lane]);
      const unsigned int v4 = __builtin_nontemporal_load(&M[(size_t)r4 * 64 + lane]);
      const unsigned int v5 = __builtin_nontemporal_load(&M[(size_t)r5 * 64 + lane]);
      const unsigned int v6 = __builtin_nontemporal_load(&M[(size_t)r6 * 64 + lane]);
      const unsigned int v7 = __builtin_nontemporal_load(&M[(size_t)r7 * 64 + lane]);
      acc0 += __uint_as_float(v0 << 16);
      acc1 += __uint_as_float(v0 & 0xFFFF0000u);
      acc0 += __uint_as_float(v1 << 16);
      acc1 += __uint_as_float(v1 & 0xFFFF0000u);
      acc0 += __uint_as_float(v2 << 16);
      acc1 += __uint_as_float(v2 & 0xFFFF0000u);
      acc0 += __uint_as_float(v3 << 16);
      acc1 += __uint_as_float(v3 & 0xFFFF0000u);
      acc0 += __uint_as_float(v4 << 16);
      acc1 += __uint_as_float(v4 & 0xFFFF0000u);
      acc0 += __uint_as_float(v5 << 16);
      acc1 += __uint_as_float(v5 & 0xFFFF0000u);
      acc0 += __uint_as_float(v6 << 16);
      acc1 += __uint_as_float(v6 & 0xFFFF0000u);
      acc0 += __uint_as_float(v7 << 16);
      acc1 += __uint_as_float(v7 & 0xFFFF0000u);
    }
    for (; e + 4 <= e1; e += 4) {
      const int r0 = srec[e], r1 = srec[e + 1], r2 = srec[e + 2],
                r3 = srec[e + 3];
      const unsigned int v0 = __builtin_nontemporal_load(&M[(size_t)r0 * 64 + lane]);
      const unsigned int v1 = __builtin_nontemporal_load(&M[(size_t)r1 * 64 + lane]);
      const unsigned int v2 = __builtin_nontemporal_load(&M[(size_t)r2 * 64 + lane]);
      const unsigned int v3 = __builtin_nontemporal_load(&M[(size_t)r3 * 64 + lane]);
      acc0 += __uint_as_float(v0 << 16);
      acc1 += __uint_as_float(v0 & 0xFFFF0000u);
      acc0 += __uint_as_float(v1 << 16);
      acc1 += __uint_as_float(v1 & 0xFFFF0000u);
      acc0 += __uint_as_float(v2 << 16);
      acc1 += __uint_as_float(v2 & 0xFFFF0000u);
      acc0 += __uint_as_float(v3 << 16);
      acc1 += __uint_as_float(v3 & 0xFFFF0000u);
    }
    for (; e < e1; ++e) {
      const unsigned int v = __builtin_nontemporal_load(&M[(size_t)srec[e] * 64 + lane]);
      acc0 += __uint_as_float(v << 16);
      acc1 += __uint_as_float(v & 0xFFFF0000u);
    }

    const float nm = norm[d];
    float* __restrict__ op = out + ((size_t)d << 7);
    float o0 = fmaf(acc0, nm, op[lane]);
    float o1 = fmaf(acc1, nm, op[64 + lane]);
    if (final_pass) {
      o0 = fmaxf(o0, 0.f);
      o1 = fmaxf(o1, 0.f);
    }
    op[lane] = o0;
    op[64 + lane] = o1;
  }
}

// Fallback (ws too small / unexpected shape): unsorted atomic edge kernel.
__global__ __launch_bounds__(256) void rgcn_edge_kernel(
    const float* __restrict__ h, const float* __restrict__ norm,
    const int* __restrict__ esrc, const int* __restrict__ edst,
    const int* __restrict__ etype, const float* __restrict__ weight,
    float* __restrict__ out, int E) {
  const int lane = threadIdx.x & 63;
  const int wid = threadIdx.x >> 6;
  const int wave0 = blockIdx.x * 4 + wid;
  const int nwaves = gridDim.x * 4;
  const int b = lane >> 4;
  const int o = lane & 15;

  for (int e = wave0; e < E; e += nwaves) {
    const int src = esrc[e];
    const int dst = edst[e];
    const int et = etype[e];
    const float s_lo = h[src * 128 + lane];
    const float s_hi = h[src * 128 + 64 + lane];
    const float nrm = norm[dst];
    const float* __restrict__ Wb = weight + et * 2048 + b * 256 + o;
    float m0 = 0.f, m1 = 0.f;
#pragma unroll
    for (int i = 0; i < 16; ++i) {
      const float a_lo = __shfl(s_lo, (lane & 48) + i, 64);
      const float a_hi = __shfl(s_hi, (lane & 48) + i, 64);
      m0 = fmaf(a_lo, Wb[i * 16], m0);
      m1 = fmaf(a_hi, Wb[1024 + i * 16], m1);
    }
    atomicAdd(&out[dst * 128 + lane], m0 * nrm);
    atomicAdd(&out[dst * 128 + 64 + lane], m1 * nrm);
  }
}

__global__ __launch_bounds__(256) void rgcn_relu_kernel(float* __restrict__ out,
                                                        int total4) {
  int i = blockIdx.x * 256 + threadIdx.x;
  const int stride = gridDim.x * 256;
  for (; i < total4; i += stride) {
    float4 v = ((float4*)out)[i];
    v.x = fmaxf(v.x, 0.f);
    v.y = fmaxf(v.y, 0.f);
    v.z = fmaxf(v.z, 0.f);
    v.w = fmaxf(v.w, 0.f);
    ((float4*)out)[i] = v;
  }
}

extern "C" void kernel_launch(void* const* d_in, const int* in_sizes, int n_in,
                              void* d_out, int out_size, void* d_ws, size_t ws_size,
                              hipStream_t stream) {
  const float* h      = (const float*)d_in[0];
  const float* norm   = (const float*)d_in[1];
  const int*   esrc   = (const int*)d_in[2];
  const int*   edst   = (const int*)d_in[3];
  const int*   etype  = (const int*)d_in[4];
  const float* weight = (const float*)d_in[5];
  const float* bias   = (const float*)d_in[6];
  const float* loop_w = (const float*)d_in[7];
  float* out = (float*)d_out;

  const int N = in_sizes[0] / 128;
  const int E = in_sizes[2];
  const int nrels = in_sizes[5] / 2048;

  rgcn_init_kernel<<<2048, 256, 0, stream>>>(h, loop_w, bias, out, N);

  // Pick the SMALLEST C (fewest passes) with S=ceil(N/C) whose footprint
  // fits ws_size. ws (dwords): cnt[bins] | row_ptr[bins+1] | cursor[bins] |
  // partial[4096] | srec[E] | M[S*16*64]
  int C = -1, S = 0;
  size_t ofs_rp = 0, ofs_cur = 0, ofs_part = 0, ofs_srec = 0, ofs_M = 0;
  if (nrels == 16 && N >= 1 && N < (1 << 26)) {
    for (int cc = 1; cc <= 64; ++cc) {
      const size_t bins = (size_t)cc * (size_t)N;
      if (bins > (size_t)4096 * 4096) break;  // scan capacity
      const int ss = (N + cc - 1) / cc;
      const size_t o_rp = (bins + 3) & ~(size_t)3;
      const size_t o_cur = (o_rp + bins + 1 + 3) & ~(size_t)3;
      const size_t o_part = (o_cur + bins + 3) & ~(size_t)3;
      const size_t o_srec = o_part + 4096;
      const size_t o_M = (o_srec + (size_t)E + 15) & ~(size_t)15;
      const size_t need = (o_M + (size_t)ss * 16 * 64) * 4;
      if (need <= ws_size) {
        C = cc; S = ss;
        ofs_rp = o_rp; ofs_cur = o_cur; ofs_part = o_part;
        ofs_srec = o_srec; ofs_M = o_M;
        break;
      }
    }
  }

  if (C >= 1) {
    const int bins = C * N;
    const int nb = (bins + 4095) / 4096;
    int* base    = (int*)d_ws;
    int* cnt     = base;
    int* row_ptr = base + ofs_rp;
    int* cursor  = base + ofs_cur;
    int* partial = base + ofs_part;
    int* srec    = base + ofs_srec;
    unsigned int* M = (unsigned int*)(base + ofs_M);

    rgcn_zero_kernel<<<1024, 256, 0, stream>>>(cnt, bins);
    rgcn_hist_kernel<<<2048, 256, 0, stream>>>(esrc, edst, cnt, E, N,
                                               (unsigned)S);
    rgcn_scan_pass1<<<nb, 1024, 0, stream>>>(cnt, partial, bins);
    rgcn_scan_pass2<<<1, 1024, 0, stream>>>(partial, nb);
    rgcn_scan_pass3<<<nb, 1024, 0, stream>>>(cnt, partial, row_ptr, cursor,
                                             bins);
    rgcn_set_kernel<<<1, 64, 0, stream>>>(row_ptr + bins, E);
    rgcn_scatter_kernel<<<2048, 256, 0, stream>>>(esrc, edst, etype, cursor,
                                                  srec, E, N, (unsigned)S);
    for (int c = 0; c < C; ++c) {
      const int cbase = c * S;
      const int cend = (cbase + S < N) ? (cbase + S) : N;
      if (cbase >= N) break;
      rgcn_precompute_kernel<<<512, 1024, 0, stream>>>(h, weight, M, cbase,
                                                       cend);
      rgcn_gather3_kernel<<<2048, 256, 0, stream>>>(
          norm, srec, row_ptr + (size_t)c * N, M, out, N,
          (c == C - 1) ? 1 : 0);
    }
  } else {
    rgcn_edge_kernel<<<4096, 256, 0, stream>>>(h, norm, esrc, edst, etype,
                                               weight, out, E);
    rgcn_relu_kernel<<<2048, 256, 0, stream>>>(out, (N * 128) / 4);
  }
}